// Round 7
// baseline (124.325 us; speedup 1.0000x reference)
//
#include <hip/hip_runtime.h>
#include <hip/hip_bf16.h>
#include <math.h>

constexpr int Bz = 4, Cc = 64, Hh = 128, Ww = 128, Kk = 9;
constexpr int HW = Hh * Ww;              // 16384
constexpr float EPSf = 1e-5f;
constexpr int CK = Cc * Kk;              // 576

typedef __attribute__((ext_vector_type(8))) short short8;
typedef __attribute__((ext_vector_type(4))) float f32x4;

__device__ __forceinline__ ushort f32_to_bf16(float f) {
    uint u = __float_as_uint(f);
    return (ushort)((u + 0x7fffu + ((u >> 16) & 1u)) >> 16);   // RNE
}

// ---- weight fragments (deform + offset-conv) in one launch ----
__global__ void frag_kernel(const float* __restrict__ w1, const float* __restrict__ w2,
                            const float* __restrict__ ow1, const float* __restrict__ ow2,
                            ushort* __restrict__ wA1, ushort* __restrict__ wA2,
                            ushort* __restrict__ oA1, ushort* __restrict__ oA2) {
    int tid = blockIdx.x * 256 + threadIdx.x;     // 2*36864 + 2*18432 = 110592
    if (tid >= 110592) return;
    const float* src; ushort* dst; int e; int cout;
    if (tid < 36864)        { src = w1;  dst = wA1; e = tid;         cout = 64; }
    else if (tid < 73728)   { src = w2;  dst = wA2; e = tid - 36864; cout = 64; }
    else if (tid < 92160)   { src = ow1; dst = oA1; e = tid - 73728; cout = 18; }
    else                    { src = ow2; dst = oA2; e = tid - 92160; cout = 18; }
    int j = e & 7, l = (e >> 3) & 63, kk = (e >> 9) % 18, wo = e / 9216;
    int oc = wo * 16 + (l & 15);
    int kidx = kk * 32 + ((l >> 4) * 8) + j;
    int tap = kidx >> 6, c = kidx & 63;
    dst[e] = (oc < cout) ? f32_to_bf16(src[oc * CK + c * 9 + tap]) : (ushort)0;
}

// ---- NCHW fp32 -> NHWC bf16 (tiled transpose), for x only ----
__global__ __launch_bounds__(256)
void nhwc_kernel(const float* __restrict__ src, ushort* __restrict__ dst) {
    __shared__ float s_t[64][65];
    int blk = blockIdx.x;                 // Bz * (HW/64) = 1024
    int p0 = (blk & 255) * 64;
    int b = blk >> 8;
    int t = threadIdx.x;
    int tp = t & 63;
    #pragma unroll
    for (int i = 0; i < 16; i++) {
        int c = i * 4 + (t >> 6);
        s_t[c][tp] = src[((size_t)(b * 64 + c)) * HW + p0 + tp];
    }
    __syncthreads();
    #pragma unroll
    for (int i = 0; i < 16; i++) {
        int pl = i * 4 + (t >> 6);
        dst[((size_t)b * HW + p0 + pl) * 64 + tp] = f32_to_bf16(s_t[tp][pl]);
    }
}

// ---- fused offset-conv + deformable conv + GN partial reduce ----
// block = 16 px of one (b,h) row, 256 threads, 8 blocks/CU resident
__global__ __launch_bounds__(256, 8)
void deform_fused_kernel(const ushort* __restrict__ xnh, const ushort* __restrict__ wA,
                         const ushort* __restrict__ owA, const float* __restrict__ bias,
                         const float* __restrict__ obias, float* __restrict__ y,
                         float* __restrict__ part) {
    __shared__ __align__(16) ushort s_a[16 * 584];    // 18,688B: A[px][tap*64+c]
    __shared__ uint   s_yx[144];                      // 576B: packed (y0,x0) per unit
    __shared__ float2 s_wyx[144];                     // 1,152B: (wy,wx) per unit
    // off_s2 aliases s_a (phase A writes, phase 0 reads, phase 1 overwrites)
    float (*off_s2)[16][18] = reinterpret_cast<float (*)[16][18]>(s_a);

    int blk = blockIdx.x;            // Bz*Hh*(Ww/16) = 4096
    int wt = blk & 7;
    int h  = (blk >> 3) & 127;
    int b  = blk >> 10;
    int w0 = wt * 16;
    int t = threadIdx.x;
    int wv = t >> 6, lane = t & 63;
    const ushort* xnb = xnh + (size_t)b * HW * 64;

    // ---- phase A: offset conv via MFMA; 4 waves = (wo 0..1) x (kh 0..1) ----
    {
        int wo = wv & 1, kh = wv >> 1;
        int g = lane >> 4, li = lane & 15;
        int px = li;
        f32x4 oacc;
        #pragma unroll
        for (int r = 0; r < 4; r++) {
            int oc = wo * 16 + g * 4 + r;
            oacc[r] = (kh == 0 && oc < 18) ? obias[oc] : 0.f;
        }
        const short8* owp = reinterpret_cast<const short8*>(owA) + (wo * 18) * 64 + lane;
        #pragma unroll
        for (int kki = 0; kki < 9; kki++) {
            int kk = kh * 9 + kki;
            int tap = kk >> 1;
            int ky = tap / 3 - 1, kx = tap - (tap / 3) * 3 - 1;
            int c0 = (kk & 1) * 32 + g * 8;
            int gy = h + ky, gx = w0 + px + kx;
            bool valid = ((unsigned)gy < 128u) && ((unsigned)gx < 128u);
            short8 bf = {0, 0, 0, 0, 0, 0, 0, 0};
            if (valid)
                bf = *reinterpret_cast<const short8*>(&xnb[(((gy << 7) + gx) << 6) + c0]);
            short8 af = owp[kk * 64];
            oacc = __builtin_amdgcn_mfma_f32_16x16x32_bf16(af, bf, oacc, 0, 0, 0);
        }
        #pragma unroll
        for (int r = 0; r < 4; r++) {
            int oc = wo * 16 + g * 4 + r;
            if (oc < 18) off_s2[kh][px][oc] = oacc[r];
        }
    }
    __syncthreads();

    // ---- phase 0: units t<144 -> compact {y0,x0,wy,wx} (s_yx/s_wyx separate) ----
    if (t < 144) {
        int px = t / 9, k = t - px * 9;
        int ky = k / 3 - 1, kx = k - (k / 3) * 3 - 1;
        float ody = off_s2[0][px][2 * k]     + off_s2[1][px][2 * k];
        float odx = off_s2[0][px][2 * k + 1] + off_s2[1][px][2 * k + 1];
        float cy = (float)(h + ky) + ody;
        float cx = (float)(w0 + px + kx) + odx;
        float fy = floorf(cy), fx = floorf(cx);
        int y0 = (int)fy, x0 = (int)fx;
        s_yx[t] = (uint)(y0 & 0xffff) | ((uint)x0 << 16);
        float2 wv2; wv2.x = cy - fy; wv2.y = cx - fx;
        s_wyx[t] = wv2;
    }
    __syncthreads();   // off_s2 reads done (s_a free), coord records visible

    // ---- phase 1: gather; 8 lanes per unit, 8 ch/lane, reconstruct corners ----
    {
        int sub = lane >> 3;               // unit slot in this iteration
        int ci  = lane & 7;                // channel group
        int co  = ci << 4;                 // byte offset of channel group
        const char* xnc = reinterpret_cast<const char*>(xnb);
        char* s_ab = reinterpret_cast<char*>(s_a);
        #pragma unroll
        for (int i = 0; i < 5; i++) {
            int lu = i * 8 + sub;
            if (lu < 36) {
                int U = wv * 36 + lu;      // unit = px*9 + tap
                int px = U / 9;
                int tap = U - px * 9;
                uint yx = s_yx[U];
                float2 wv2 = s_wyx[U];
                int y0 = (short)(yx & 0xffffu);
                int x0 = (short)(yx >> 16);
                float wy = wv2.x, wx = wv2.y;
                int y1 = y0 + 1, x1 = x0 + 1;
                bool vy0 = (unsigned)y0 < 128u, vy1 = (unsigned)y1 < 128u;
                bool vx0 = (unsigned)x0 < 128u, vx1 = (unsigned)x1 < 128u;
                int yc0 = min(max(y0, 0), 127), yc1 = min(max(y1, 0), 127);
                int xc0 = min(max(x0, 0), 127), xc1 = min(max(x1, 0), 127);
                uint a00 = (uint)(((yc0 << 7) + xc0) << 7) + co;
                uint a01 = (uint)(((yc0 << 7) + xc1) << 7) + co;
                uint a10 = (uint)(((yc1 << 7) + xc0) << 7) + co;
                uint a11 = (uint)(((yc1 << 7) + xc1) << 7) + co;
                float w00 = (vy0 && vx0) ? (1.f - wy) * (1.f - wx) : 0.f;
                float w01 = (vy0 && vx1) ? (1.f - wy) * wx : 0.f;
                float w10 = (vy1 && vx0) ? wy * (1.f - wx) : 0.f;
                float w11 = (vy1 && vx1) ? wy * wx : 0.f;
                uint4 v00 = *reinterpret_cast<const uint4*>(xnc + a00);
                uint4 v01 = *reinterpret_cast<const uint4*>(xnc + a01);
                uint4 v10 = *reinterpret_cast<const uint4*>(xnc + a10);
                uint4 v11 = *reinterpret_cast<const uint4*>(xnc + a11);
                float a0, a1, a2, a3, a4, a5, a6, a7;
                #define LO(u) __uint_as_float((u) << 16)
                #define HI(u) __uint_as_float((u) & 0xffff0000u)
                a0 = w00 * LO(v00.x); a1 = w00 * HI(v00.x);
                a2 = w00 * LO(v00.y); a3 = w00 * HI(v00.y);
                a4 = w00 * LO(v00.z); a5 = w00 * HI(v00.z);
                a6 = w00 * LO(v00.w); a7 = w00 * HI(v00.w);
                a0 = fmaf(w01, LO(v01.x), a0); a1 = fmaf(w01, HI(v01.x), a1);
                a2 = fmaf(w01, LO(v01.y), a2); a3 = fmaf(w01, HI(v01.y), a3);
                a4 = fmaf(w01, LO(v01.z), a4); a5 = fmaf(w01, HI(v01.z), a5);
                a6 = fmaf(w01, LO(v01.w), a6); a7 = fmaf(w01, HI(v01.w), a7);
                a0 = fmaf(w10, LO(v10.x), a0); a1 = fmaf(w10, HI(v10.x), a1);
                a2 = fmaf(w10, LO(v10.y), a2); a3 = fmaf(w10, HI(v10.y), a3);
                a4 = fmaf(w10, LO(v10.z), a4); a5 = fmaf(w10, HI(v10.z), a5);
                a6 = fmaf(w10, LO(v10.w), a6); a7 = fmaf(w10, HI(v10.w), a7);
                a0 = fmaf(w11, LO(v11.x), a0); a1 = fmaf(w11, HI(v11.x), a1);
                a2 = fmaf(w11, LO(v11.y), a2); a3 = fmaf(w11, HI(v11.y), a3);
                a4 = fmaf(w11, LO(v11.z), a4); a5 = fmaf(w11, HI(v11.z), a5);
                a6 = fmaf(w11, LO(v11.w), a6); a7 = fmaf(w11, HI(v11.w), a7);
                #undef LO
                #undef HI
                float2 p01; p01.x = a0; p01.y = a1;
                float2 p23; p23.x = a2; p23.y = a3;
                float2 p45; p45.x = a4; p45.y = a5;
                float2 p67; p67.x = a6; p67.y = a7;
                __hip_bfloat162 b01 = __float22bfloat162_rn(p01);
                __hip_bfloat162 b23 = __float22bfloat162_rn(p23);
                __hip_bfloat162 b45 = __float22bfloat162_rn(p45);
                __hip_bfloat162 b67 = __float22bfloat162_rn(p67);
                uint4 outv;
                outv.x = *reinterpret_cast<uint*>(&b01);
                outv.y = *reinterpret_cast<uint*>(&b23);
                outv.z = *reinterpret_cast<uint*>(&b45);
                outv.w = *reinterpret_cast<uint*>(&b67);
                *reinterpret_cast<uint4*>(s_ab + px * 1168 + tap * 128 + co) = outv;
            }
        }
    }
    __syncthreads();

    // ---- phase 2: deform MFMA. wave = wo (oc tile); D[16oc][16px] ----
    int wo = wv;
    int g = lane >> 4, li = lane & 15;
    f32x4 acc;
    const float* bp = bias + wo * 16 + g * 4;
    acc.x = bp[0]; acc.y = bp[1]; acc.z = bp[2]; acc.w = bp[3];
    const short8* ap = reinterpret_cast<const short8*>(wA) + (wo * 18) * 64 + lane;
    const ushort* sp = s_a + li * 584 + g * 8;
    #pragma unroll
    for (int kk = 0; kk < 18; kk++) {
        short8 af = ap[kk * 64];                                    // weights (arg0)
        short8 bf = *reinterpret_cast<const short8*>(sp + kk * 32); // samples (arg1)
        acc = __builtin_amdgcn_mfma_f32_16x16x32_bf16(af, bf, acc, 0, 0, 0);
    }
    size_t ybase = ((size_t)(b * 64 + wo * 16 + g * 4)) * HW + h * Ww + w0 + li;
    y[ybase]           = acc.x;
    y[ybase + HW]      = acc.y;
    y[ybase + 2 * HW]  = acc.z;
    y[ybase + 3 * HW]  = acc.w;

    // ---- epilogue: GN partial sums for this block's 1024 values ----
    float s  = acc.x + acc.y + acc.z + acc.w;
    float s2 = acc.x * acc.x + acc.y * acc.y + acc.z * acc.z + acc.w * acc.w;
    #pragma unroll
    for (int o = 32; o > 0; o >>= 1) {
        s  += __shfl_down(s, o);
        s2 += __shfl_down(s2, o);
    }
    float* redbuf = reinterpret_cast<float*>(s_yx);   // s_yx dead now
    if (lane == 0) { redbuf[wv * 2] = s; redbuf[wv * 2 + 1] = s2; }
    __syncthreads();
    if (t == 0) {
        float a = 0.f, c2 = 0.f;
        #pragma unroll
        for (int i = 0; i < 4; i++) { a += redbuf[i * 2]; c2 += redbuf[i * 2 + 1]; }
        part[blk * 2]     = a;
        part[blk * 2 + 1] = c2;
    }
}

// shared per-block reduction of one sample's 1024 partial pairs -> (mean, rsqrt)
__device__ __forceinline__ void gn_reduce_stats(const float* __restrict__ part, int b,
                                                int t, float& m_out, float& rs_out) {
    __shared__ float ls[4][2];
    __shared__ float s_ms[2];
    int base = b * 1024 + t;
    float s  = part[base * 2]            + part[(base + 256) * 2]
             + part[(base + 512) * 2]    + part[(base + 768) * 2];
    float s2 = part[base * 2 + 1]        + part[(base + 256) * 2 + 1]
             + part[(base + 512) * 2 + 1] + part[(base + 768) * 2 + 1];
    #pragma unroll
    for (int o = 32; o > 0; o >>= 1) {
        s  += __shfl_down(s, o);
        s2 += __shfl_down(s2, o);
    }
    int wave = t >> 6, lane = t & 63;
    if (lane == 0) { ls[wave][0] = s; ls[wave][1] = s2; }
    __syncthreads();
    if (t == 0) {
        float a = 0.f, c = 0.f;
        #pragma unroll
        for (int i = 0; i < 4; i++) { a += ls[i][0]; c += ls[i][1]; }
        const float n = (float)(Cc * HW);
        float m = a / n;
        float var = c / n - m * m;
        s_ms[0] = m;
        s_ms[1] = rsqrtf(var + EPSf);
    }
    __syncthreads();
    m_out = s_ms[0];
    rs_out = s_ms[1];
}

// ---- block-1 finalize: GN-stats + normalize+ReLU+residual -> h1 + hnh ----
__global__ __launch_bounds__(256)
void gn_fin1_kernel(const float* __restrict__ y, const float* __restrict__ res,
                    const float* __restrict__ g, const float* __restrict__ be,
                    const float* __restrict__ part, float* __restrict__ h1,
                    ushort* __restrict__ hnh) {
    __shared__ float s_t[64][65];
    int blk = blockIdx.x;                 // Bz * (HW/64) = 1024
    int p0 = (blk & 255) * 64;
    int b = blk >> 8;
    int t = threadIdx.x;
    int tp = t & 63;
    float m, rs;
    gn_reduce_stats(part, b, t, m, rs);
    #pragma unroll
    for (int i = 0; i < 16; i++) {
        int c = i * 4 + (t >> 6);
        size_t idx = ((size_t)(b * 64 + c)) * HW + p0 + tp;
        float v = (y[idx] - m) * rs * g[c] + be[c];
        v = fmaxf(v, 0.f) + res[idx];
        h1[idx] = v;
        s_t[c][tp] = v;
    }
    __syncthreads();
    #pragma unroll
    for (int i = 0; i < 16; i++) {
        int pl = i * 4 + (t >> 6);
        hnh[((size_t)b * HW + p0 + pl) * 64 + tp] = f32_to_bf16(s_t[tp][pl]);
    }
}

// ---- block-2 finalize: GN-stats + normalize + ReLU + residual -> out ----
__global__ __launch_bounds__(256)
void gn_fin2_kernel(const float* __restrict__ y, const float* __restrict__ res,
                    const float* __restrict__ g, const float* __restrict__ be,
                    const float* __restrict__ part, float* __restrict__ out) {
    int idx = (blockIdx.x * 256 + threadIdx.x) * 4;   // B*C*H*W / 4 threads
    int c = (idx >> 14) & 63;
    int b = idx >> 20;
    float m, rs;
    gn_reduce_stats(part, b, threadIdx.x, m, rs);
    float gc = g[c], bc = be[c];
    float4 yv = *reinterpret_cast<const float4*>(y + idx);
    float4 rv = *reinterpret_cast<const float4*>(res + idx);
    float4 o;
    o.x = fmaxf((yv.x - m) * rs * gc + bc, 0.f) + rv.x;
    o.y = fmaxf((yv.y - m) * rs * gc + bc, 0.f) + rv.y;
    o.z = fmaxf((yv.z - m) * rs * gc + bc, 0.f) + rv.z;
    o.w = fmaxf((yv.w - m) * rs * gc + bc, 0.f) + rv.w;
    *reinterpret_cast<float4*>(out + idx) = o;
}

extern "C" void kernel_launch(void* const* d_in, const int* in_sizes, int n_in,
                              void* d_out, int out_size, void* d_ws, size_t ws_size,
                              hipStream_t stream) {
    const float* x   = (const float*)d_in[0];
    const float* w1  = (const float*)d_in[1];
    const float* b1  = (const float*)d_in[2];
    const float* ow1 = (const float*)d_in[3];
    const float* ob1 = (const float*)d_in[4];
    const float* g1  = (const float*)d_in[5];
    const float* be1 = (const float*)d_in[6];
    const float* w2  = (const float*)d_in[7];
    const float* b2  = (const float*)d_in[8];
    const float* ow2 = (const float*)d_in[9];
    const float* ob2 = (const float*)d_in[10];
    const float* g2  = (const float*)d_in[11];
    const float* be2 = (const float*)d_in[12];
    float* out = (float*)d_out;

    float* ws    = (float*)d_ws;
    float* ybuf  = ws;                                   // 4,194,304 f
    float* h1    = ybuf + (size_t)Bz * Cc * HW;          // 4,194,304 f
    ushort* xnh  = (ushort*)(h1 + (size_t)Bz * Cc * HW); // 4,194,304 bf16
    ushort* hnh  = xnh + (size_t)Bz * HW * 64;           // 4,194,304 bf16
    ushort* wA1  = hnh + (size_t)Bz * HW * 64;           // 36,864 bf16
    ushort* wA2  = wA1 + 36864;                          // 36,864 bf16
    ushort* owA1 = wA2 + 36864;                          // 18,432 bf16
    ushort* owA2 = owA1 + 18432;                         // 18,432 bf16
    float* part  = (float*)(owA2 + 18432);               // 8192 f

    frag_kernel<<<(110592 + 255) / 256, 256, 0, stream>>>(w1, w2, ow1, ow2, wA1, wA2, owA1, owA2);
    nhwc_kernel<<<Bz * (HW / 64), 256, 0, stream>>>(x, xnh);

    // block 1: offset-conv + deform_conv + GN-partial (fused) -> fin1
    deform_fused_kernel<<<Bz * Hh * (Ww / 16), 256, 0, stream>>>(xnh, wA1, owA1, b1, ob1, ybuf, part);
    gn_fin1_kernel<<<Bz * (HW / 64), 256, 0, stream>>>(ybuf, x, g1, be1, part, h1, hnh);

    // block 2: same, residual on h1, elementwise finalize to out
    deform_fused_kernel<<<Bz * Hh * (Ww / 16), 256, 0, stream>>>(hnh, wA2, owA2, b2, ob2, ybuf, part);
    gn_fin2_kernel<<<Bz * Cc * HW / 1024, 256, 0, stream>>>(ybuf, h1, g2, be2, part, out);
}